// Round 1
// baseline (1172.092 us; speedup 1.0000x reference)
//
#include <hip/hip_runtime.h>
#include <math.h>

#define HID 128
#define NR 8
#define NN 512
#define BB 2
#define NNODE (BB*NN)            // 1024
#define NEDGE (BB*NN*NN)         // 524288
#define CUTR 10.0f

// ws layout (float offsets)
#define WS_A   0
#define WS_B   (NNODE*256)                       // 262144
#define WS_G   (2*NNODE*256)                     // 524288
#define WS_CT  (WS_G + NEDGE*16)                 // 8912896
#define WS_MSG (WS_CT + NEDGE)                   // 9437184
// total = 9568256 floats = ~36.5 MB

// out layout (float offsets)
#define OUT_H   0
#define OUT_POS (NNODE*HID)                      // 131072
#define OUT_VEL (OUT_POS + NNODE*2)              // 133120

__device__ __forceinline__ float silu_f(float x) {
  return x / (1.f + __expf(-x));
}

// ---------------------------------------------------------------- K1
// A[n][c] = eb1[c] + ew1[264][c] + sum_k h[n][k]*ew1[k][c]
// Bm[n][c] =                       sum_k h[n][k]*ew1[128+k][c]
__global__ __launch_bounds__(256)
void k1_precompute(const float* __restrict__ h, const float* __restrict__ ew1,
                   const float* __restrict__ eb1, float* __restrict__ ws) {
  int node = blockIdx.x;
  int c = threadIdx.x;
  __shared__ float sh_h[HID];
  if (c < HID) sh_h[c] = h[node*HID + c];
  __syncthreads();
  float a  = eb1[c] + ew1[264*256 + c];
  float bm = 0.f;
#pragma unroll 4
  for (int k = 0; k < HID; ++k) {
    float hv = sh_h[k];
    a  += hv * ew1[k*256 + c];
    bm += hv * ew1[(128+k)*256 + c];
  }
  ws[WS_A + node*256 + c] = a;
  ws[WS_B + node*256 + c] = bm;
}

// ---------------------------------------------------------------- K2
// Per-edge geometry: G16 = [radial(8), cos(m t) m=1..4, sin(m t) m=1..4], cutoff
__global__ __launch_bounds__(256)
void k2_geometry(const float* __restrict__ pos, float* __restrict__ ws) {
  int e = blockIdx.x * 256 + threadIdx.x;          // < NEDGE
  int j = e & (NN-1);
  int i = (e >> 9) & (NN-1);
  int b = e >> 18;
  float pix = pos[(b*NN+i)*2+0], piy = pos[(b*NN+i)*2+1];
  float pjx = pos[(b*NN+j)*2+0], pjy = pos[(b*NN+j)*2+1];
  float dx = pix - pjx, dy = piy - pjy;
  float d = sqrtf(dx*dx + dy*dy);

  float g[16];
  const float inv_w = (float)NR / CUTR;            // 1/1.25
#pragma unroll
  for (int k = 0; k < NR; ++k) {
    float ctr = (CUTR * (float)k) / 7.0f;          // linspace(0,10,8)
    float t = (d - ctr) * inv_w;
    g[k] = __expf(-t*t);
  }
  float theta = atan2f(dy, dx);
  float c1, s1;
  __sincosf(theta, &s1, &c1);
  float c2 = c1*c1 - s1*s1,  s2 = 2.f*s1*c1;
  float c3 = c2*c1 - s2*s1,  s3 = s2*c1 + c2*s1;
  float c4 = c3*c1 - s3*s1,  s4 = s3*c1 + c3*s1;
  g[8]=c1; g[9]=c2; g[10]=c3; g[11]=c4;
  g[12]=s1; g[13]=s2; g[14]=s3; g[15]=s4;

  float4* gp = (float4*)(ws + WS_G) + (size_t)e*4;
  gp[0] = make_float4(g[0],g[1],g[2],g[3]);
  gp[1] = make_float4(g[4],g[5],g[6],g[7]);
  gp[2] = make_float4(g[8],g[9],g[10],g[11]);
  gp[3] = make_float4(g[12],g[13],g[14],g[15]);

  float cut = (d < CUTR) ? 0.5f*(cosf((float)M_PI * d / CUTR) + 1.f) : 0.f;
  ws[WS_CT + e] = cut;
}

// ---------------------------------------------------------------- K3
// One block per (b,i). Loop j in 16 chunks of 32.
#define CH 32
#define PADH 260
#define PADE 132

__global__ __launch_bounds__(256)
void k3_edge(const float* __restrict__ pos, const float* __restrict__ vel,
             const float* __restrict__ ew1,
             const float* __restrict__ ew2, const float* __restrict__ eb2,
             const float* __restrict__ cw1, const float* __restrict__ cb1,
             const float* __restrict__ cw2, const float* __restrict__ cb2,
             float* __restrict__ ws, float* __restrict__ out) {
  __shared__ float sh_H[CH][PADH];
  __shared__ float sh_E[CH][PADE];
  __shared__ float sh_msum[8][PADE];
  __shared__ float sh_red[CH][33];

  int bid = blockIdx.x;
  int b = bid >> 9, i = bid & (NN-1);
  int node = b*NN + i;
  int t = threadIdx.x;
  int jg = t >> 5, cg = t & 31;
  int j0 = jg*4, c0 = cg*4;
  size_t ebase = (size_t)node * NN;

  float pix = pos[node*2+0], piy = pos[node*2+1];

  // per-thread W1g column (c = t), 16 geometry rows of ew1
  float wg[16];
#pragma unroll
  for (int k = 0; k < 8; ++k) wg[k] = ew1[(256+k)*256 + t];
#pragma unroll
  for (int m = 0; m < 4; ++m) {
    wg[8+m]  = ew1[(265+m)*256 + t];
    wg[12+m] = ew1[(269+m)*256 + t];
  }
  float a_val = ws[WS_A + node*256 + t];

  float4 ebv  = ((const float4*)eb2)[cg];
  float4 cbv  = ((const float4*)cb1)[cg];
  float4 c2v  = ((const float4*)cw2)[cg];

  float msgacc = 0.f;
  float updx = 0.f, updy = 0.f;

  for (int jb = 0; jb < NN; jb += CH) {
    // ---- phase 1: build H tile = silu(A_i + B_j + G@W1g), c = t
#pragma unroll 2
    for (int jj = 0; jj < CH; ++jj) {
      int j = jb + jj;
      const float4* G4 = (const float4*)(ws + WS_G) + (ebase + j)*4;
      float4 g0 = G4[0], g1 = G4[1], g2 = G4[2], g3 = G4[3];
      float pre = a_val + ws[WS_B + (b*NN + j)*256 + t];
      pre += g0.x*wg[0] + g0.y*wg[1] + g0.z*wg[2] + g0.w*wg[3]
           + g1.x*wg[4] + g1.y*wg[5] + g1.z*wg[6] + g1.w*wg[7]
           + g2.x*wg[8] + g2.y*wg[9] + g2.z*wg[10]+ g2.w*wg[11]
           + g3.x*wg[12]+ g3.y*wg[13]+ g3.z*wg[14]+ g3.w*wg[15];
      sh_H[jj][t] = silu_f(pre);
    }
    __syncthreads();

    // ---- phase 2: e = H @ ew2 + eb2, thread tile 4j x 4c
    float acc[4][4];
#pragma unroll
    for (int r = 0; r < 4; ++r) {
      acc[r][0]=ebv.x; acc[r][1]=ebv.y; acc[r][2]=ebv.z; acc[r][3]=ebv.w;
    }
#pragma unroll 4
    for (int k = 0; k < 256; ++k) {
      float4 w = ((const float4*)(ew2 + k*HID))[cg];
      float h0 = sh_H[j0+0][k], h1 = sh_H[j0+1][k];
      float h2 = sh_H[j0+2][k], h3 = sh_H[j0+3][k];
      acc[0][0] += h0*w.x; acc[0][1] += h0*w.y; acc[0][2] += h0*w.z; acc[0][3] += h0*w.w;
      acc[1][0] += h1*w.x; acc[1][1] += h1*w.y; acc[1][2] += h1*w.z; acc[1][3] += h1*w.w;
      acc[2][0] += h2*w.x; acc[2][1] += h2*w.y; acc[2][2] += h2*w.z; acc[2][3] += h2*w.w;
      acc[3][0] += h3*w.x; acc[3][1] += h3*w.y; acc[3][2] += h3*w.z; acc[3][3] += h3*w.w;
    }
    // cutoff, stage e tile, partial msg sums
    float4 ms = make_float4(0.f,0.f,0.f,0.f);
#pragma unroll
    for (int r = 0; r < 4; ++r) {
      float cut = ws[WS_CT + ebase + jb + j0 + r];
      float4 ev;
      ev.x = acc[r][0]*cut; ev.y = acc[r][1]*cut;
      ev.z = acc[r][2]*cut; ev.w = acc[r][3]*cut;
      *(float4*)&sh_E[j0+r][c0] = ev;
      ms.x += ev.x; ms.y += ev.y; ms.z += ev.z; ms.w += ev.w;
    }
    *(float4*)&sh_msum[jg][c0] = ms;
    __syncthreads();

    // msg aggregation (c = t < 128)
    if (t < HID) {
      float s = 0.f;
#pragma unroll
      for (int g = 0; g < 8; ++g) s += sh_msum[g][t];
      msgacc += s;
    }

    // ---- phase 3: C1 = silu(E @ cw1 + cb1); partial dots with cw2
    float acc2[4][4];
#pragma unroll
    for (int r = 0; r < 4; ++r) {
      acc2[r][0]=cbv.x; acc2[r][1]=cbv.y; acc2[r][2]=cbv.z; acc2[r][3]=cbv.w;
    }
#pragma unroll 4
    for (int k = 0; k < HID; ++k) {
      float4 w = ((const float4*)(cw1 + k*HID))[cg];
      float e0 = sh_E[j0+0][k], e1 = sh_E[j0+1][k];
      float e2 = sh_E[j0+2][k], e3 = sh_E[j0+3][k];
      acc2[0][0] += e0*w.x; acc2[0][1] += e0*w.y; acc2[0][2] += e0*w.z; acc2[0][3] += e0*w.w;
      acc2[1][0] += e1*w.x; acc2[1][1] += e1*w.y; acc2[1][2] += e1*w.z; acc2[1][3] += e1*w.w;
      acc2[2][0] += e2*w.x; acc2[2][1] += e2*w.y; acc2[2][2] += e2*w.z; acc2[2][3] += e2*w.w;
      acc2[3][0] += e3*w.x; acc2[3][1] += e3*w.y; acc2[3][2] += e3*w.z; acc2[3][3] += e3*w.w;
    }
#pragma unroll
    for (int r = 0; r < 4; ++r) {
      float p = silu_f(acc2[r][0])*c2v.x + silu_f(acc2[r][1])*c2v.y
              + silu_f(acc2[r][2])*c2v.z + silu_f(acc2[r][3])*c2v.w;
      sh_red[j0+r][cg] = p;
    }
    __syncthreads();

    // ---- phase 4: per-j coord weight, upd accumulation (t < 32)
    if (t < CH) {
      int j = jb + t;
      float s = cb2[0];
#pragma unroll
      for (int g = 0; g < 32; ++g) s += sh_red[t][g];
      float pjx = pos[(b*NN + j)*2 + 0], pjy = pos[(b*NN + j)*2 + 1];
      float ux = (pix - pjx) * s, uy = (piy - pjy) * s;
#pragma unroll
      for (int off = 16; off > 0; off >>= 1) {
        ux += __shfl_down(ux, off);
        uy += __shfl_down(uy, off);
      }
      if (t == 0) { updx += ux; updy += uy; }
    }
    __syncthreads();
  }

  if (t < HID) ws[WS_MSG + (size_t)node*HID + t] = msgacc;
  if (t == 0) {
    out[OUT_POS + node*2+0] = pix + updx;
    out[OUT_POS + node*2+1] = piy + updy;
    out[OUT_VEL + node*2+0] = vel[node*2+0] + 0.1f*updx;
    out[OUT_VEL + node*2+1] = vel[node*2+1] + 0.1f*updy;
  }
}

// ---------------------------------------------------------------- K4
__global__ __launch_bounds__(128)
void k4_node(const float* __restrict__ h, const float* __restrict__ ws,
             const float* __restrict__ nw1, const float* __restrict__ nb1,
             const float* __restrict__ nw2, const float* __restrict__ nb2,
             const float* __restrict__ lng, const float* __restrict__ lnb,
             float* __restrict__ out) {
  int node = blockIdx.x;
  int t = threadIdx.x;
  __shared__ float sh_in[256];
  __shared__ float sh_hid[HID];
  __shared__ float rbuf[4];

  sh_in[t]       = h[node*HID + t];
  sh_in[HID + t] = ws[WS_MSG + (size_t)node*HID + t];
  __syncthreads();

  float s = nb1[t];
#pragma unroll 4
  for (int k = 0; k < 256; ++k) s += sh_in[k] * nw1[k*HID + t];
  sh_hid[t] = silu_f(s);
  __syncthreads();

  float hn = nb2[t];
#pragma unroll 4
  for (int k = 0; k < HID; ++k) hn += sh_hid[k] * nw2[k*HID + t];
  float x = sh_in[t] + hn;

  float v1 = x, v2 = x*x;
#pragma unroll
  for (int off = 32; off > 0; off >>= 1) {
    v1 += __shfl_down(v1, off);
    v2 += __shfl_down(v2, off);
  }
  if ((t & 63) == 0) { rbuf[t>>6] = v1; rbuf[2 + (t>>6)] = v2; }
  __syncthreads();
  float mu  = (rbuf[0] + rbuf[1]) * (1.f/HID);
  float var = (rbuf[2] + rbuf[3]) * (1.f/HID) - mu*mu;
  float inv = 1.f / sqrtf(var + 1e-5f);
  out[OUT_H + node*HID + t] = (x - mu) * inv * lng[t] + lnb[t];
}

// ---------------------------------------------------------------- launch
extern "C" void kernel_launch(void* const* d_in, const int* in_sizes, int n_in,
                              void* d_out, int out_size, void* d_ws, size_t ws_size,
                              hipStream_t stream) {
  (void)in_sizes; (void)n_in; (void)out_size; (void)ws_size;
  const float* h   = (const float*)d_in[0];
  const float* pos = (const float*)d_in[1];
  const float* vel = (const float*)d_in[2];
  const float* ew1 = (const float*)d_in[3];
  const float* eb1 = (const float*)d_in[4];
  const float* ew2 = (const float*)d_in[5];
  const float* eb2 = (const float*)d_in[6];
  const float* cw1 = (const float*)d_in[7];
  const float* cb1 = (const float*)d_in[8];
  const float* cw2 = (const float*)d_in[9];
  const float* cb2 = (const float*)d_in[10];
  const float* nw1 = (const float*)d_in[11];
  const float* nb1 = (const float*)d_in[12];
  const float* nw2 = (const float*)d_in[13];
  const float* nb2 = (const float*)d_in[14];
  const float* lng = (const float*)d_in[15];
  const float* lnb = (const float*)d_in[16];
  float* out = (float*)d_out;
  float* ws  = (float*)d_ws;

  hipLaunchKernelGGL(k1_precompute, dim3(NNODE), dim3(256), 0, stream, h, ew1, eb1, ws);
  hipLaunchKernelGGL(k2_geometry, dim3(NEDGE/256), dim3(256), 0, stream, pos, ws);
  hipLaunchKernelGGL(k3_edge, dim3(NNODE), dim3(256), 0, stream,
                     pos, vel, ew1, ew2, eb2, cw1, cb1, cw2, cb2, ws, out);
  hipLaunchKernelGGL(k4_node, dim3(NNODE), dim3(128), 0, stream,
                     h, ws, nw1, nb1, nw2, nb2, lng, lnb, out);
}

// Round 2
// 777.671 us; speedup vs baseline: 1.5072x; 1.5072x over previous
//
#include <hip/hip_runtime.h>
#include <math.h>

#define HID 128
#define NN 512
#define BB 2
#define NNODE (BB*NN)            // 1024
#define NEDGE (BB*NN*NN)         // 524288
#define CUTR 10.0f

// ---- ws layout, float offsets
#define WS_A    0                 // [1024][256] fp32
#define WS_B    262144            // [1024][256] fp32
#define WS_CT   524288            // [NEDGE] fp32 cutoff
#define WS_MSG  1048576           // [1024][128] fp32
// ---- ws layout, short offsets (ws viewed as short*)
#define SG_OFF   2359296                  // [NEDGE][16] bf16 geometry (A-frag order)
#define SE2T_OFF (SG_OFF + NEDGE*16)      // ew2^T bf16 [128][256]
#define SC1T_OFF (SE2T_OFF + 32768)       // cw1^T bf16 [128][128]
#define SW1G_OFF (SC1T_OFF + 16384)       // W1g^T bf16 [256][16]

// ---- out layout (float offsets)
#define OUT_H   0
#define OUT_POS (NNODE*HID)       // 131072
#define OUT_VEL (OUT_POS + NNODE*2)

typedef __attribute__((ext_vector_type(8)))  short short8;
typedef __attribute__((ext_vector_type(8)))  __bf16 bf16x8;
typedef __attribute__((ext_vector_type(16))) float float16;

__device__ __forceinline__ float silu_f(float x) {
  return x / (1.f + __expf(-x));
}
__device__ __forceinline__ short f2bf(float x) {
  union { float f; unsigned u; } v; v.f = x;
  unsigned r = v.u + 0x7FFF + ((v.u >> 16) & 1);
  return (short)(r >> 16);
}
__device__ __forceinline__ bf16x8 as_bf(short8 s) {
  return __builtin_bit_cast(bf16x8, s);
}
__device__ __forceinline__ float16 zero16() {
  float16 z;
#pragma unroll
  for (int r = 0; r < 16; ++r) z[r] = 0.f;
  return z;
}

// ---------------------------------------------------------------- K0
// Transpose + bf16-convert weights: ew2^T, cw1^T, W1g^T (geometry rows of ew1).
__global__ __launch_bounds__(256)
void k0_prep(const float* __restrict__ ew1, const float* __restrict__ ew2,
             const float* __restrict__ cw1, short* __restrict__ wsS) {
  int idx = blockIdx.x * 256 + threadIdx.x;
  if (idx < 32768) {
    int c = idx >> 8, k = idx & 255;
    wsS[SE2T_OFF + c*256 + k] = f2bf(ew2[k*HID + c]);
  } else if (idx < 49152) {
    int i2 = idx - 32768; int c = i2 >> 7, k = i2 & 127;
    wsS[SC1T_OFF + c*128 + k] = f2bf(cw1[k*HID + c]);
  } else if (idx < 53248) {
    int i3 = idx - 49152; int c = i3 >> 4, f = i3 & 15;
    // feature order: radial 0..7 -> ew1 rows 256..263; cos m -> 265..268; sin m -> 269..272
    int row = (f < 8) ? (256 + f) : ((f < 12) ? (257 + f) : (257 + f));
    // f=8..11 -> 265..268 ; f=12..15 -> 269..272  (both are 257+f)
    wsS[SW1G_OFF + c*16 + f] = f2bf(ew1[row*256 + c]);
  }
}

// ---------------------------------------------------------------- K1
// A[n][c] = eb1[c] + ew1[264][c] + sum_k h[n][k]*ew1[k][c]      (const-1 angular row folded)
// Bm[n][c] =                       sum_k h[n][k]*ew1[128+k][c]
__global__ __launch_bounds__(256)
void k1_precompute(const float* __restrict__ h, const float* __restrict__ ew1,
                   const float* __restrict__ eb1, float* __restrict__ ws) {
  int node = blockIdx.x;
  int c = threadIdx.x;
  __shared__ float sh_h[HID];
  if (c < HID) sh_h[c] = h[node*HID + c];
  __syncthreads();
  float a  = eb1[c] + ew1[264*256 + c];
  float bm = 0.f;
#pragma unroll 4
  for (int k = 0; k < HID; ++k) {
    float hv = sh_h[k];
    a  += hv * ew1[k*256 + c];
    bm += hv * ew1[(128+k)*256 + c];
  }
  ws[WS_A + node*256 + c] = a;
  ws[WS_B + node*256 + c] = bm;
}

// ---------------------------------------------------------------- K2
// Per-edge geometry, bf16, in MFMA-A-fragment feature order; cutoff fp32.
__global__ __launch_bounds__(256)
void k2_geometry(const float* __restrict__ pos, float* __restrict__ ws,
                 short* __restrict__ wsS) {
  int e = blockIdx.x * 256 + threadIdx.x;
  int j = e & (NN-1);
  int i = (e >> 9) & (NN-1);
  int b = e >> 18;
  float pix = pos[(b*NN+i)*2+0], piy = pos[(b*NN+i)*2+1];
  float pjx = pos[(b*NN+j)*2+0], pjy = pos[(b*NN+j)*2+1];
  float dx = pix - pjx, dy = piy - pjy;
  float d = sqrtf(dx*dx + dy*dy);

  short8 ga, gb;
  const float inv_w = (float)8 / CUTR;
#pragma unroll
  for (int k = 0; k < 8; ++k) {
    float ctr = (CUTR * (float)k) / 7.0f;
    float t = (d - ctr) * inv_w;
    ga[k] = f2bf(__expf(-t*t));
  }
  float theta = atan2f(dy, dx);
  float c1, s1;
  __sincosf(theta, &s1, &c1);
  float c2 = c1*c1 - s1*s1,  s2 = 2.f*s1*c1;
  float c3 = c2*c1 - s2*s1,  s3 = s2*c1 + c2*s1;
  float c4 = c3*c1 - s3*s1,  s4 = s3*c1 + c3*s1;
  gb[0]=f2bf(c1); gb[1]=f2bf(c2); gb[2]=f2bf(c3); gb[3]=f2bf(c4);
  gb[4]=f2bf(s1); gb[5]=f2bf(s2); gb[6]=f2bf(s3); gb[7]=f2bf(s4);

  short8* gp = (short8*)(wsS + SG_OFF + (size_t)e*16);
  gp[0] = ga; gp[1] = gb;

  ws[WS_CT + e] = (d < CUTR) ? 0.5f*(__cosf((float)M_PI * d / CUTR) + 1.f) : 0.f;
}

// ---------------------------------------------------------------- K3
// One block per (b,i); 4 waves; wave w owns output cols [32w,32w+32).
// Per 32-j chunk: MFMA geometry-GEMM (K=16, C-init = A_i + Bm_j), silu -> bf16 LDS,
// MFMA GEMM1 (K=256) -> e (cutoff, msg acc, bf16 LDS), MFMA GEMM2 (K=128) ->
// silu, dot cw2, reduce -> coord weight -> upd.
__global__ __launch_bounds__(256, 2)
void k3_edge(const float* __restrict__ pos, const float* __restrict__ vel,
             const float* __restrict__ eb2, const float* __restrict__ cb1,
             const float* __restrict__ cw2, const float* __restrict__ cb2,
             float* ws, float* __restrict__ out) {
  short* wsS = (short*)ws;
  __shared__ __align__(16) short shH[32*256];   // bf16, xor-swizzled 16B chunks
  __shared__ __align__(16) short shE[32*128];   // bf16, xor-swizzled 16B chunks
  __shared__ float shred[32][4];

  const int t = threadIdx.x;
  const int w = t >> 6, l = t & 63, lo = l & 31, hl = l >> 5, hl4 = hl * 4;
  const int node = blockIdx.x;                  // b*512 + i
  const int b = node >> 9;
  const int bN = b * NN;
  const size_t ebase = (size_t)node * NN;

  // ---- preload B-fragments (registers, reused across all 16 chunks)
  bf16x8 wb1[16];
  {
    const short* p = wsS + SE2T_OFF + (32*w + lo)*256 + hl*8;
#pragma unroll
    for (int s = 0; s < 16; ++s) wb1[s] = as_bf(*(const short8*)(p + s*16));
  }
  bf16x8 wb2[8];
  {
    const short* p = wsS + SC1T_OFF + (32*w + lo)*128 + hl*8;
#pragma unroll
    for (int s = 0; s < 8; ++s) wb2[s] = as_bf(*(const short8*)(p + s*16));
  }
  const bf16x8 wg0 = as_bf(*(const short8*)(wsS + SW1G_OFF + (64*w + lo)*16 + hl*8));
  const bf16x8 wg1 = as_bf(*(const short8*)(wsS + SW1G_OFF + (64*w + 32 + lo)*16 + hl*8));

  const float a0   = ws[WS_A + node*256 + 64*w + lo];
  const float a1   = ws[WS_A + node*256 + 64*w + 32 + lo];
  const float ebv  = eb2[32*w + lo];
  const float cb1v = cb1[32*w + lo];
  const float c2v  = cw2[32*w + lo];
  const float cb2v = cb2[0];
  const float pix  = pos[node*2], piy = pos[node*2+1];

  float msgacc[16];
#pragma unroll
  for (int r = 0; r < 16; ++r) msgacc[r] = 0.f;
  float updx = 0.f, updy = 0.f;

  for (int jb = 0; jb < NN; jb += 32) {
    // ---- phase 1: Hpre = G @ W1g + (A_i + Bm_j); silu -> shH (bf16)
    const bf16x8 gf = as_bf(*(const short8*)(wsS + SG_OFF + (ebase + jb + lo)*16 + hl*8));
    const float* bmBase = ws + WS_B + (size_t)(bN + jb)*256;
#pragma unroll
    for (int ct = 0; ct < 2; ++ct) {
      const int colg = 64*w + 32*ct + lo;
      const float av = ct ? a1 : a0;
      float16 ci;
#pragma unroll
      for (int r = 0; r < 16; ++r) {
        int row = (r&3) + 8*(r>>2) + hl4;
        ci[r] = bmBase[row*256 + colg] + av;
      }
      float16 hp = __builtin_amdgcn_mfma_f32_32x32x16_bf16(gf, ct ? wg1 : wg0, ci, 0, 0, 0);
      const int ck = colg >> 3;
#pragma unroll
      for (int r = 0; r < 16; ++r) {
        int row = (r&3) + 8*(r>>2) + hl4;
        shH[row*256 + (((ck ^ row) & 31) << 3) + (colg & 7)] = f2bf(silu_f(hp[r]));
      }
    }
    __syncthreads();

    // ---- GEMM1: e = H @ ew2 (K=256), 16 MFMA
    float16 acc1 = zero16();
#pragma unroll
    for (int s = 0; s < 16; ++s) {
      const int ck = 2*s + hl;
      bf16x8 af = as_bf(*(const short8*)(shH + lo*256 + (((ck ^ lo) & 31) << 3)));
      acc1 = __builtin_amdgcn_mfma_f32_32x32x16_bf16(af, wb1[s], acc1, 0, 0, 0);
    }
    // epilogue: +bias, *cutoff, msg acc, bf16 -> shE
    float4 cv[4];
#pragma unroll
    for (int g = 0; g < 4; ++g)
      cv[g] = *(const float4*)(ws + WS_CT + ebase + jb + 8*g + hl4);
    const int kE = 32*w + lo;
    const int ckE = kE >> 3;
#pragma unroll
    for (int r = 0; r < 16; ++r) {
      int row = (r&3) + 8*(r>>2) + hl4;
      float ev = (acc1[r] + ebv) * ((const float*)&cv[r>>2])[r&3];
      msgacc[r] += ev;
      shE[row*128 + (((ckE ^ (row & 15)) & 15) << 3) + (kE & 7)] = f2bf(ev);
    }
    __syncthreads();

    // ---- GEMM2: c1 = E @ cw1 (K=128), 8 MFMA
    float16 acc2 = zero16();
#pragma unroll
    for (int s = 0; s < 8; ++s) {
      const int ck = 2*s + hl;
      bf16x8 af = as_bf(*(const short8*)(shE + lo*128 + (((ck ^ (lo & 15)) & 15) << 3)));
      acc2 = __builtin_amdgcn_mfma_f32_32x32x16_bf16(af, wb2[s], acc2, 0, 0, 0);
    }
    // epilogue: silu, * cw2[col], reduce over 32 cols per half-wave
#pragma unroll
    for (int r = 0; r < 16; ++r) {
      float p = silu_f(acc2[r] + cb1v) * c2v;
#pragma unroll
      for (int m = 1; m < 32; m <<= 1) p += __shfl_xor(p, m, 32);
      if (lo == 0) shred[(r&3) + 8*(r>>2) + hl4][w] = p;
    }
    __syncthreads();

    // ---- phase 4: coord weight -> upd (wave 0)
    if (t < 32) {
      float s = cb2v + shred[t][0] + shred[t][1] + shred[t][2] + shred[t][3];
      int jn = bN + jb + t;
      float ux = (pix - pos[jn*2])   * s;
      float uy = (piy - pos[jn*2+1]) * s;
#pragma unroll
      for (int off = 16; off > 0; off >>= 1) {
        ux += __shfl_down(ux, off, 32);
        uy += __shfl_down(uy, off, 32);
      }
      if (t == 0) { updx += ux; updy += uy; }
    }
  }

  // ---- msg writeout: sum rows (16 regs) + other half-wave
  float m = 0.f;
#pragma unroll
  for (int r = 0; r < 16; ++r) m += msgacc[r];
  m += __shfl_xor(m, 32, 64);
  if (l < 32) ws[WS_MSG + node*128 + 32*w + lo] = m;

  if (t == 0) {
    out[OUT_POS + node*2+0] = pix + updx;
    out[OUT_POS + node*2+1] = piy + updy;
    out[OUT_VEL + node*2+0] = vel[node*2+0] + 0.1f*updx;
    out[OUT_VEL + node*2+1] = vel[node*2+1] + 0.1f*updy;
  }
}

// ---------------------------------------------------------------- K4
__global__ __launch_bounds__(128)
void k4_node(const float* __restrict__ h, const float* __restrict__ ws,
             const float* __restrict__ nw1, const float* __restrict__ nb1,
             const float* __restrict__ nw2, const float* __restrict__ nb2,
             const float* __restrict__ lng, const float* __restrict__ lnb,
             float* __restrict__ out) {
  int node = blockIdx.x;
  int t = threadIdx.x;
  __shared__ float sh_in[256];
  __shared__ float sh_hid[HID];
  __shared__ float rbuf[4];

  sh_in[t]       = h[node*HID + t];
  sh_in[HID + t] = ws[WS_MSG + (size_t)node*HID + t];
  __syncthreads();

  float s = nb1[t];
#pragma unroll 4
  for (int k = 0; k < 256; ++k) s += sh_in[k] * nw1[k*HID + t];
  sh_hid[t] = silu_f(s);
  __syncthreads();

  float hn = nb2[t];
#pragma unroll 4
  for (int k = 0; k < HID; ++k) hn += sh_hid[k] * nw2[k*HID + t];
  float x = sh_in[t] + hn;

  float v1 = x, v2 = x*x;
#pragma unroll
  for (int off = 32; off > 0; off >>= 1) {
    v1 += __shfl_down(v1, off);
    v2 += __shfl_down(v2, off);
  }
  if ((t & 63) == 0) { rbuf[t>>6] = v1; rbuf[2 + (t>>6)] = v2; }
  __syncthreads();
  float mu  = (rbuf[0] + rbuf[1]) * (1.f/HID);
  float var = (rbuf[2] + rbuf[3]) * (1.f/HID) - mu*mu;
  float inv = 1.f / sqrtf(var + 1e-5f);
  out[OUT_H + node*HID + t] = (x - mu) * inv * lng[t] + lnb[t];
}

// ---------------------------------------------------------------- launch
extern "C" void kernel_launch(void* const* d_in, const int* in_sizes, int n_in,
                              void* d_out, int out_size, void* d_ws, size_t ws_size,
                              hipStream_t stream) {
  (void)in_sizes; (void)n_in; (void)out_size; (void)ws_size;
  const float* h   = (const float*)d_in[0];
  const float* pos = (const float*)d_in[1];
  const float* vel = (const float*)d_in[2];
  const float* ew1 = (const float*)d_in[3];
  const float* eb1 = (const float*)d_in[4];
  const float* ew2 = (const float*)d_in[5];
  const float* eb2 = (const float*)d_in[6];
  const float* cw1 = (const float*)d_in[7];
  const float* cb1 = (const float*)d_in[8];
  const float* cw2 = (const float*)d_in[9];
  const float* cb2 = (const float*)d_in[10];
  const float* nw1 = (const float*)d_in[11];
  const float* nb1 = (const float*)d_in[12];
  const float* nw2 = (const float*)d_in[13];
  const float* nb2 = (const float*)d_in[14];
  const float* lng = (const float*)d_in[15];
  const float* lnb = (const float*)d_in[16];
  float* out = (float*)d_out;
  float* ws  = (float*)d_ws;
  short* wsS = (short*)d_ws;

  hipLaunchKernelGGL(k0_prep, dim3(208), dim3(256), 0, stream, ew1, ew2, cw1, wsS);
  hipLaunchKernelGGL(k1_precompute, dim3(NNODE), dim3(256), 0, stream, h, ew1, eb1, ws);
  hipLaunchKernelGGL(k2_geometry, dim3(NEDGE/256), dim3(256), 0, stream, pos, ws, wsS);
  hipLaunchKernelGGL(k3_edge, dim3(NNODE), dim3(256), 0, stream,
                     pos, vel, eb2, cb1, cw2, cb2, ws, out);
  hipLaunchKernelGGL(k4_node, dim3(NNODE), dim3(128), 0, stream,
                     h, ws, nw1, nb1, nw2, nb2, lng, lnb, out);
}

// Round 3
// 626.242 us; speedup vs baseline: 1.8716x; 1.2418x over previous
//
#include <hip/hip_runtime.h>
#include <math.h>

#define HID 128
#define NN 512
#define NNODE 1024
#define CUTR 10.0f

// ---- ws layout, float offsets
#define WS_A    0            // [1024][256] fp32  (A_i + bias + const-angular row)
#define WS_MSG  262144       // [1024][128] fp32  msg_agg
// ---- ws layout, ushort offsets (ws viewed as unsigned short*)
#define SBMT_OFF 786432                  // BmT bf16 [2][256][512]  (c-major, j inner)
#define SE2T_OFF (SBMT_OFF + 262144)     // ew2^T bf16 [128][256]
#define SC1T_OFF (SE2T_OFF + 32768)      // cw1^T bf16 [128][128]
#define SW1G_OFF (SC1T_OFF + 16384)      // W1g^T bf16 [256][16]

// ---- out layout (float offsets)
#define OUT_POS 131072
#define OUT_VEL 133120

typedef __attribute__((ext_vector_type(8)))  short short8;
typedef __attribute__((ext_vector_type(4)))  unsigned short ushort4v;
typedef __attribute__((ext_vector_type(8)))  __bf16 bf16x8;
typedef __attribute__((ext_vector_type(16))) float float16;

__device__ __forceinline__ float silu_f(float x) {
  return x / (1.f + __expf(-x));
}
__device__ __forceinline__ short f2bf(float x) {
  union { float f; unsigned u; } v; v.f = x;
  unsigned r = v.u + 0x7FFF + ((v.u >> 16) & 1);
  return (short)(r >> 16);
}
__device__ __forceinline__ float bf2f(unsigned short u) {
  union { unsigned u; float f; } v; v.u = ((unsigned)u) << 16;
  return v.f;
}
__device__ __forceinline__ bf16x8 as_bf(short8 s) {
  return __builtin_bit_cast(bf16x8, s);
}
__device__ __forceinline__ float16 zero16() {
  float16 z;
#pragma unroll
  for (int r = 0; r < 16; ++r) z[r] = 0.f;
  return z;
}

// ---------------------------------------------------------------- K0
// Transpose + bf16-convert weights: ew2^T, cw1^T, W1g^T (geometry rows of ew1).
__global__ __launch_bounds__(256)
void k0_prep(const float* __restrict__ ew1, const float* __restrict__ ew2,
             const float* __restrict__ cw1, unsigned short* __restrict__ wsU) {
  int idx = blockIdx.x * 256 + threadIdx.x;
  if (idx < 32768) {
    int c = idx >> 8, k = idx & 255;
    wsU[SE2T_OFF + c*256 + k] = (unsigned short)f2bf(ew2[k*HID + c]);
  } else if (idx < 49152) {
    int i2 = idx - 32768; int c = i2 >> 7, k = i2 & 127;
    wsU[SC1T_OFF + c*128 + k] = (unsigned short)f2bf(cw1[k*HID + c]);
  } else if (idx < 53248) {
    int i3 = idx - 49152; int c = i3 >> 4, f = i3 & 15;
    // f: 0..7 radial -> ew1 rows 256..263; 8..11 cos -> 265..268; 12..15 sin -> 269..272
    int row = (f < 8) ? (256 + f) : (257 + f);
    wsU[SW1G_OFF + c*16 + f] = (unsigned short)f2bf(ew1[row*256 + c]);
  }
}

// ---------------------------------------------------------------- K1
// A[n][c] = eb1[c] + ew1[264][c] + sum_k h[n][k]*ew1[k][c]   (fp32, [node][256])
// BmT[b][c][j] = bf16( sum_k h[b,j][k]*ew1[128+k][c] )
__global__ __launch_bounds__(256)
void k1_precompute(const float* __restrict__ h, const float* __restrict__ ew1,
                   const float* __restrict__ eb1, float* __restrict__ ws,
                   unsigned short* __restrict__ wsU) {
  int node = blockIdx.x;
  int c = threadIdx.x;
  __shared__ float sh_h[HID];
  if (c < HID) sh_h[c] = h[node*HID + c];
  __syncthreads();
  float a  = eb1[c] + ew1[264*256 + c];
  float bm = 0.f;
#pragma unroll 4
  for (int k = 0; k < HID; ++k) {
    float hv = sh_h[k];
    a  += hv * ew1[k*256 + c];
    bm += hv * ew1[(128+k)*256 + c];
  }
  ws[WS_A + node*256 + c] = a;
  int b = node >> 9, j = node & 511;
  wsU[SBMT_OFF + b*131072 + c*512 + j] = (unsigned short)f2bf(bm);
}

// ---------------------------------------------------------------- K3
// One block per (b,i); 4 waves; wave w owns output cols [32w,32w+32).
// Geometry computed inline (no precomputed edge stream).
__global__ __launch_bounds__(256, 4)
void k3_edge(const float* __restrict__ pos, const float* __restrict__ vel,
             const float* __restrict__ eb2, const float* __restrict__ cb1,
             const float* __restrict__ cw2, const float* __restrict__ cb2,
             float* __restrict__ ws, float* __restrict__ out) {
  const short* wsS = (const short*)ws;
  const unsigned short* wsU = (const unsigned short*)ws;
  __shared__ __align__(16) short shH[32*256];   // bf16, xor-swizzled 16B chunks
  __shared__ __align__(16) short shE[32*128];   // bf16, xor-swizzled 16B chunks
  __shared__ float shred[12];

  const int t = threadIdx.x;
  const int w = t >> 6, l = t & 63, lo = l & 31, hl = l >> 5, hl4 = hl * 4;
  const int node = blockIdx.x;
  const int b = node >> 9;
  const int bN = b * NN;

  // persistent B-fragments: cw1^T (8 MFMA steps) + W1g^T (2 halves)
  bf16x8 wb2[8];
  {
    const short* p = wsS + SC1T_OFF + (32*w + lo)*128 + hl*8;
#pragma unroll
    for (int s = 0; s < 8; ++s) wb2[s] = as_bf(*(const short8*)(p + s*16));
  }
  const bf16x8 wg0 = as_bf(*(const short8*)(wsS + SW1G_OFF + (64*w + lo)*16 + hl*8));
  const bf16x8 wg1 = as_bf(*(const short8*)(wsS + SW1G_OFF + (64*w + 32 + lo)*16 + hl*8));

  const float a0   = ws[WS_A + node*256 + 64*w + lo];
  const float a1   = ws[WS_A + node*256 + 64*w + 32 + lo];
  const float ebv  = eb2[32*w + lo];
  const float cb1v = cb1[32*w + lo];
  const float c2v  = cw2[32*w + lo];
  const float cb2c = cb2[0] * (1.f/128.f);
  const float pix  = pos[node*2], piy = pos[node*2+1];

  float msum = 0.f;
  float S = 0.f, SX = 0.f, SY = 0.f;

  for (int jb = 0; jb < NN; jb += 32) {
    // ---- inline geometry for j = jb + lo
    const int jn = bN + jb + lo;
    const float pjx = pos[2*jn], pjy = pos[2*jn+1];
    const float dx = pix - pjx, dy = piy - pjy;
    const float d = sqrtf(dx*dx + dy*dy);
    const float cutv = (d < CUTR) ? 0.5f*(__cosf((float)M_PI*(1.f/CUTR)*d) + 1.f) : 0.f;
    short8 gs;
    if (hl == 0) {
      // radial features 0..7
#pragma unroll
      for (int k = 0; k < 8; ++k) {
        float ctr = (CUTR * (float)k) / 7.0f;
        float tt = (d - ctr) * 0.8f;
        gs[k] = f2bf(__expf(-tt*tt));
      }
    } else {
      // angular features: cos(m th), sin(m th) via recurrence on (dx/d, dy/d)
      float invd = 1.f / (d + 1e-8f);
      float c1 = dx * invd, s1 = dy * invd;
      if (d == 0.f) { c1 = 1.f; s1 = 0.f; }   // matches atan2(0,0)=0
      float c2 = c1*c1 - s1*s1, s2 = 2.f*s1*c1;
      float c3 = c2*c1 - s2*s1, s3 = s2*c1 + c2*s1;
      float c4 = c3*c1 - s3*s1, s4 = s3*c1 + c3*s1;
      gs[0]=f2bf(c1); gs[1]=f2bf(c2); gs[2]=f2bf(c3); gs[3]=f2bf(c4);
      gs[4]=f2bf(s1); gs[5]=f2bf(s2); gs[6]=f2bf(s3); gs[7]=f2bf(s4);
    }
    const bf16x8 gf = as_bf(gs);

    // ---- phase 1: Hpre = G @ W1g + (A_i + Bm_j); silu -> shH (bf16, swizzled)
#pragma unroll
    for (int ct = 0; ct < 2; ++ct) {
      const int colg = 64*w + 32*ct + lo;
      const float av = ct ? a1 : a0;
      const unsigned short* bt = wsU + SBMT_OFF + b*131072 + colg*512 + jb + hl4;
      float16 ci;
#pragma unroll
      for (int g = 0; g < 4; ++g) {
        ushort4v v4 = *(const ushort4v*)(bt + 8*g);
        ci[4*g+0] = bf2f(v4[0]) + av;
        ci[4*g+1] = bf2f(v4[1]) + av;
        ci[4*g+2] = bf2f(v4[2]) + av;
        ci[4*g+3] = bf2f(v4[3]) + av;
      }
      float16 hp = __builtin_amdgcn_mfma_f32_32x32x16_bf16(gf, ct ? wg1 : wg0, ci, 0, 0, 0);
      const int ck = colg >> 3;
#pragma unroll
      for (int r = 0; r < 16; ++r) {
        int row = (r&3) + 8*(r>>2) + hl4;
        shH[row*256 + (((ck ^ row) & 31) << 3) + (colg & 7)] = f2bf(silu_f(hp[r]));
      }
    }
    __syncthreads();

    // ---- GEMM1: e = H @ ew2 (K=256), weights streamed from L2
    float16 acc1 = zero16();
    {
      const short* wp1 = wsS + SE2T_OFF + (32*w + lo)*256 + hl*8;
#pragma unroll
      for (int s = 0; s < 16; ++s) {
        bf16x8 wv = as_bf(*(const short8*)(wp1 + 16*s));
        const int ck = 2*s + hl;
        bf16x8 af = as_bf(*(const short8*)(shH + lo*256 + (((ck ^ lo) & 31) << 3)));
        acc1 = __builtin_amdgcn_mfma_f32_32x32x16_bf16(af, wv, acc1, 0, 0, 0);
      }
    }
    // epilogue 1: +bias, *cutoff (shfl), msg acc, bf16 -> shE
    const int kE = 32*w + lo;
    const int ckE = kE >> 3;
#pragma unroll
    for (int r = 0; r < 16; ++r) {
      int row = (r&3) + 8*(r>>2) + hl4;
      float cr = __shfl(cutv, row, 32);
      float ev = (acc1[r] + ebv) * cr;
      msum += ev;
      shE[row*128 + (((ckE ^ (row & 15)) & 15) << 3) + (kE & 7)] = f2bf(ev);
    }
    __syncthreads();

    // ---- GEMM2: c1 = E @ cw1 (K=128)
    float16 acc2 = zero16();
#pragma unroll
    for (int s = 0; s < 8; ++s) {
      const int ck = 2*s + hl;
      bf16x8 af = as_bf(*(const short8*)(shE + lo*128 + (((ck ^ (lo & 15)) & 15) << 3)));
      acc2 = __builtin_amdgcn_mfma_f32_32x32x16_bf16(af, wb2[s], acc2, 0, 0, 0);
    }
    // epilogue 2: silu, *cw2, accumulate S / SX / SY (upd = pos_i*S - S*pos_j)
#pragma unroll
    for (int r = 0; r < 16; ++r) {
      int row = (r&3) + 8*(r>>2) + hl4;
      float p = silu_f(acc2[r] + cb1v) * c2v + cb2c;
      S += p;
      SX += p * __shfl(pjx, row, 32);
      SY += p * __shfl(pjy, row, 32);
    }
  }

  // ---- msg writeout (combine the two k-halves)
  msum += __shfl_xor(msum, 32);
  if (l < 32) ws[WS_MSG + node*128 + 32*w + lo] = msum;

  // ---- coordinate update reduction
#pragma unroll
  for (int off = 32; off > 0; off >>= 1) {
    S  += __shfl_xor(S, off);
    SX += __shfl_xor(SX, off);
    SY += __shfl_xor(SY, off);
  }
  if (l == 0) { shred[w] = S; shred[4 + w] = SX; shred[8 + w] = SY; }
  __syncthreads();
  if (t == 0) {
    float St  = shred[0] + shred[1] + shred[2]  + shred[3];
    float SXt = shred[4] + shred[5] + shred[6]  + shred[7];
    float SYt = shred[8] + shred[9] + shred[10] + shred[11];
    float updx = pix*St - SXt, updy = piy*St - SYt;
    out[OUT_POS + node*2+0] = pix + updx;
    out[OUT_POS + node*2+1] = piy + updy;
    out[OUT_VEL + node*2+0] = vel[node*2+0] + 0.1f*updx;
    out[OUT_VEL + node*2+1] = vel[node*2+1] + 0.1f*updy;
  }
}

// ---------------------------------------------------------------- K4
__global__ __launch_bounds__(128)
void k4_node(const float* __restrict__ h, const float* __restrict__ ws,
             const float* __restrict__ nw1, const float* __restrict__ nb1,
             const float* __restrict__ nw2, const float* __restrict__ nb2,
             const float* __restrict__ lng, const float* __restrict__ lnb,
             float* __restrict__ out) {
  int node = blockIdx.x;
  int t = threadIdx.x;
  __shared__ float sh_in[256];
  __shared__ float sh_hid[HID];
  __shared__ float rbuf[4];

  sh_in[t]       = h[node*HID + t];
  sh_in[HID + t] = ws[WS_MSG + (size_t)node*HID + t];
  __syncthreads();

  float s = nb1[t];
#pragma unroll 4
  for (int k = 0; k < 256; ++k) s += sh_in[k] * nw1[k*HID + t];
  sh_hid[t] = silu_f(s);
  __syncthreads();

  float hn = nb2[t];
#pragma unroll 4
  for (int k = 0; k < HID; ++k) hn += sh_hid[k] * nw2[k*HID + t];
  float x = sh_in[t] + hn;

  float v1 = x, v2 = x*x;
#pragma unroll
  for (int off = 32; off > 0; off >>= 1) {
    v1 += __shfl_down(v1, off);
    v2 += __shfl_down(v2, off);
  }
  if ((t & 63) == 0) { rbuf[t>>6] = v1; rbuf[2 + (t>>6)] = v2; }
  __syncthreads();
  float mu  = (rbuf[0] + rbuf[1]) * (1.f/HID);
  float var = (rbuf[2] + rbuf[3]) * (1.f/HID) - mu*mu;
  float inv = 1.f / sqrtf(var + 1e-5f);
  out[node*HID + t] = (x - mu) * inv * lng[t] + lnb[t];
}

// ---------------------------------------------------------------- launch
extern "C" void kernel_launch(void* const* d_in, const int* in_sizes, int n_in,
                              void* d_out, int out_size, void* d_ws, size_t ws_size,
                              hipStream_t stream) {
  (void)in_sizes; (void)n_in; (void)out_size; (void)ws_size;
  const float* h   = (const float*)d_in[0];
  const float* pos = (const float*)d_in[1];
  const float* vel = (const float*)d_in[2];
  const float* ew1 = (const float*)d_in[3];
  const float* eb1 = (const float*)d_in[4];
  const float* ew2 = (const float*)d_in[5];
  const float* eb2 = (const float*)d_in[6];
  const float* cw1 = (const float*)d_in[7];
  const float* cb1 = (const float*)d_in[8];
  const float* cw2 = (const float*)d_in[9];
  const float* cb2 = (const float*)d_in[10];
  const float* nw1 = (const float*)d_in[11];
  const float* nb1 = (const float*)d_in[12];
  const float* nw2 = (const float*)d_in[13];
  const float* nb2 = (const float*)d_in[14];
  const float* lng = (const float*)d_in[15];
  const float* lnb = (const float*)d_in[16];
  float* out = (float*)d_out;
  float* ws  = (float*)d_ws;
  unsigned short* wsU = (unsigned short*)d_ws;

  hipLaunchKernelGGL(k0_prep, dim3(208), dim3(256), 0, stream, ew1, ew2, cw1, wsU);
  hipLaunchKernelGGL(k1_precompute, dim3(NNODE), dim3(256), 0, stream, h, ew1, eb1, ws, wsU);
  hipLaunchKernelGGL(k3_edge, dim3(NNODE), dim3(256), 0, stream,
                     pos, vel, eb2, cb1, cw2, cb2, ws, out);
  hipLaunchKernelGGL(k4_node, dim3(NNODE), dim3(128), 0, stream,
                     h, ws, nw1, nb1, nw2, nb2, lng, lnb, out);
}

// Round 4
// 398.469 us; speedup vs baseline: 2.9415x; 1.5716x over previous
//
#include <hip/hip_runtime.h>
#include <math.h>

#define HID 128
#define NN 512
#define NNODE 1024
#define CUTR 10.0f

// ---- ws layout, float offsets
#define WS_A    0            // [1024][256] fp32  (A_i + bias + const-angular row)
#define WS_MSG  262144       // [1024][128] fp32  msg_agg
// ---- ws layout, ushort offsets (ws viewed as unsigned short*)
#define SBMT_OFF 786432                  // BmT bf16 [2][256][512]  (c-major, j inner)
#define SE2T_OFF (SBMT_OFF + 262144)     // ew2^T bf16 [128][256]
#define SC1T_OFF (SE2T_OFF + 32768)      // cw1^T bf16 [128][128]
#define SW1G_OFF (SC1T_OFF + 16384)      // W1g^T bf16 [256][16]

// ---- out layout (float offsets)
#define OUT_POS 131072
#define OUT_VEL 133120

typedef __attribute__((ext_vector_type(8)))  short short8;
typedef __attribute__((ext_vector_type(4)))  unsigned short ushort4v;
typedef __attribute__((ext_vector_type(8)))  __bf16 bf16x8;
typedef __attribute__((ext_vector_type(16))) float float16;

__device__ __forceinline__ float silu_f(float x) {
  return x / (1.f + __expf(-x));
}
__device__ __forceinline__ short f2bf(float x) {
  union { float f; unsigned u; } v; v.f = x;
  unsigned r = v.u + 0x7FFF + ((v.u >> 16) & 1);
  return (short)(r >> 16);
}
__device__ __forceinline__ float bf2f(unsigned short u) {
  union { unsigned u; float f; } v; v.u = ((unsigned)u) << 16;
  return v.f;
}
__device__ __forceinline__ bf16x8 as_bf(short8 s) {
  return __builtin_bit_cast(bf16x8, s);
}
__device__ __forceinline__ float16 zero16() {
  float16 z;
#pragma unroll
  for (int r = 0; r < 16; ++r) z[r] = 0.f;
  return z;
}

// ---------------------------------------------------------------- K0
// Transpose + bf16-convert weights: ew2^T, cw1^T, W1g^T (geometry rows of ew1).
__global__ __launch_bounds__(256)
void k0_prep(const float* __restrict__ ew1, const float* __restrict__ ew2,
             const float* __restrict__ cw1, unsigned short* __restrict__ wsU) {
  int idx = blockIdx.x * 256 + threadIdx.x;
  if (idx < 32768) {
    int c = idx >> 8, k = idx & 255;
    wsU[SE2T_OFF + c*256 + k] = (unsigned short)f2bf(ew2[k*HID + c]);
  } else if (idx < 49152) {
    int i2 = idx - 32768; int c = i2 >> 7, k = i2 & 127;
    wsU[SC1T_OFF + c*128 + k] = (unsigned short)f2bf(cw1[k*HID + c]);
  } else if (idx < 53248) {
    int i3 = idx - 49152; int c = i3 >> 4, f = i3 & 15;
    // f: 0..7 radial -> ew1 rows 256..263; 8..11 cos -> 265..268; 12..15 sin -> 269..272
    int row = (f < 8) ? (256 + f) : (257 + f);
    wsU[SW1G_OFF + c*16 + f] = (unsigned short)f2bf(ew1[row*256 + c]);
  }
}

// ---------------------------------------------------------------- K1
// A[n][c] = eb1[c] + ew1[264][c] + sum_k h[n][k]*ew1[k][c]   (fp32, [node][256])
// BmT[b][c][j] = bf16( sum_k h[b,j][k]*ew1[128+k][c] )
__global__ __launch_bounds__(256)
void k1_precompute(const float* __restrict__ h, const float* __restrict__ ew1,
                   const float* __restrict__ eb1, float* __restrict__ ws,
                   unsigned short* __restrict__ wsU) {
  int node = blockIdx.x;
  int c = threadIdx.x;
  __shared__ float sh_h[HID];
  if (c < HID) sh_h[c] = h[node*HID + c];
  __syncthreads();
  float a  = eb1[c] + ew1[264*256 + c];
  float bm = 0.f;
#pragma unroll 4
  for (int k = 0; k < HID; ++k) {
    float hv = sh_h[k];
    a  += hv * ew1[k*256 + c];
    bm += hv * ew1[(128+k)*256 + c];
  }
  ws[WS_A + node*256 + c] = a;
  int b = node >> 9, j = node & 511;
  wsU[SBMT_OFF + b*131072 + c*512 + j] = (unsigned short)f2bf(bm);
}

// ---------------------------------------------------------------- K3
// One block per (b,i); 4 waves; wave w owns output cols [32w,32w+32).
// Geometry computed inline. No min-waves bound: let the allocator use ~150
// regs so NOTHING spills (launch_bounds(256,4) forced a 64/64 VGPR/AGPR
// split and 98 MB of scratch writes in round 3).
__global__ __launch_bounds__(256)
void k3_edge(const float* __restrict__ pos, const float* __restrict__ vel,
             const float* __restrict__ eb2, const float* __restrict__ cb1,
             const float* __restrict__ cw2, const float* __restrict__ cb2,
             float* __restrict__ ws, float* __restrict__ out) {
  const short* wsS = (const short*)ws;
  const unsigned short* wsU = (const unsigned short*)ws;
  __shared__ __align__(16) short shH[32*256];   // bf16, xor-swizzled 16B chunks
  __shared__ __align__(16) short shE[32*128];   // bf16, xor-swizzled 16B chunks
  __shared__ float shred[12];

  const int t = threadIdx.x;
  const int w = t >> 6, l = t & 63, lo = l & 31, hl = l >> 5, hl4 = hl * 4;
  const int node = blockIdx.x;
  const int b = node >> 9;
  const int bN = b * NN;

  // persistent B-fragments: cw1^T (8 MFMA steps, reused 16x) + W1g^T (2 halves)
  bf16x8 wb2[8];
  {
    const short* p = wsS + SC1T_OFF + (32*w + lo)*128 + hl*8;
#pragma unroll
    for (int s = 0; s < 8; ++s) wb2[s] = as_bf(*(const short8*)(p + s*16));
  }
  const bf16x8 wg0 = as_bf(*(const short8*)(wsS + SW1G_OFF + (64*w + lo)*16 + hl*8));
  const bf16x8 wg1 = as_bf(*(const short8*)(wsS + SW1G_OFF + (64*w + 32 + lo)*16 + hl*8));

  const float a0   = ws[WS_A + node*256 + 64*w + lo];
  const float a1   = ws[WS_A + node*256 + 64*w + 32 + lo];
  const float ebv  = eb2[32*w + lo];
  const float cb1v = cb1[32*w + lo];
  const float c2v  = cw2[32*w + lo];
  const float cb2c = cb2[0] * (1.f/128.f);
  const float pix  = pos[node*2], piy = pos[node*2+1];

  float msum = 0.f;
  float S = 0.f, SX = 0.f, SY = 0.f;

  for (int jb = 0; jb < NN; jb += 32) {
    // ---- inline geometry for j = jb + lo
    const int jn = bN + jb + lo;
    const float pjx = pos[2*jn], pjy = pos[2*jn+1];
    const float dx = pix - pjx, dy = piy - pjy;
    const float d = sqrtf(dx*dx + dy*dy);
    const float cutv = (d < CUTR) ? 0.5f*(__cosf((float)M_PI*(1.f/CUTR)*d) + 1.f) : 0.f;
    short8 gs;
    if (hl == 0) {
      // radial features 0..7
#pragma unroll
      for (int k = 0; k < 8; ++k) {
        float ctr = (CUTR * (float)k) / 7.0f;
        float tt = (d - ctr) * 0.8f;
        gs[k] = f2bf(__expf(-tt*tt));
      }
    } else {
      // angular features: cos(m th), sin(m th) via recurrence on (dx/d, dy/d)
      float invd = 1.f / (d + 1e-8f);
      float c1 = dx * invd, s1 = dy * invd;
      if (d == 0.f) { c1 = 1.f; s1 = 0.f; }   // matches atan2(0,0)=0
      float c2 = c1*c1 - s1*s1, s2 = 2.f*s1*c1;
      float c3 = c2*c1 - s2*s1, s3 = s2*c1 + c2*s1;
      float c4 = c3*c1 - s3*s1, s4 = s3*c1 + c3*s1;
      gs[0]=f2bf(c1); gs[1]=f2bf(c2); gs[2]=f2bf(c3); gs[3]=f2bf(c4);
      gs[4]=f2bf(s1); gs[5]=f2bf(s2); gs[6]=f2bf(s3); gs[7]=f2bf(s4);
    }
    const bf16x8 gf = as_bf(gs);

    // ---- phase 1: Hpre = G @ W1g + (A_i + Bm_j); silu -> shH (bf16, swizzled)
#pragma unroll
    for (int ct = 0; ct < 2; ++ct) {
      const int colg = 64*w + 32*ct + lo;
      const float av = ct ? a1 : a0;
      const unsigned short* bt = wsU + SBMT_OFF + b*131072 + colg*512 + jb + hl4;
      float16 ci;
#pragma unroll
      for (int g = 0; g < 4; ++g) {
        ushort4v v4 = *(const ushort4v*)(bt + 8*g);
        ci[4*g+0] = bf2f(v4[0]) + av;
        ci[4*g+1] = bf2f(v4[1]) + av;
        ci[4*g+2] = bf2f(v4[2]) + av;
        ci[4*g+3] = bf2f(v4[3]) + av;
      }
      float16 hp = __builtin_amdgcn_mfma_f32_32x32x16_bf16(gf, ct ? wg1 : wg0, ci, 0, 0, 0);
      const int ck = colg >> 3;
#pragma unroll
      for (int r = 0; r < 16; ++r) {
        int row = (r&3) + 8*(r>>2) + hl4;
        shH[row*256 + (((ck ^ row) & 31) << 3) + (colg & 7)] = f2bf(silu_f(hp[r]));
      }
    }
    __syncthreads();

    // ---- GEMM1: e = H @ ew2 (K=256), weights streamed from L2.
    // unroll 4: cap in-flight weight vectors (full unroll hoisted 16x4 regs).
    float16 acc1 = zero16();
    {
      const short* wp1 = wsS + SE2T_OFF + (32*w + lo)*256 + hl*8;
#pragma unroll 4
      for (int s = 0; s < 16; ++s) {
        bf16x8 wv = as_bf(*(const short8*)(wp1 + 16*s));
        const int ck = 2*s + hl;
        bf16x8 af = as_bf(*(const short8*)(shH + lo*256 + (((ck ^ lo) & 31) << 3)));
        acc1 = __builtin_amdgcn_mfma_f32_32x32x16_bf16(af, wv, acc1, 0, 0, 0);
      }
    }
    // epilogue 1: +bias, *cutoff (shfl), msg acc, bf16 -> shE
    const int kE = 32*w + lo;
    const int ckE = kE >> 3;
#pragma unroll
    for (int r = 0; r < 16; ++r) {
      int row = (r&3) + 8*(r>>2) + hl4;
      float cr = __shfl(cutv, row, 32);
      float ev = (acc1[r] + ebv) * cr;
      msum += ev;
      shE[row*128 + (((ckE ^ (row & 15)) & 15) << 3) + (kE & 7)] = f2bf(ev);
    }
    __syncthreads();

    // ---- GEMM2: c1 = E @ cw1 (K=128)
    float16 acc2 = zero16();
#pragma unroll
    for (int s = 0; s < 8; ++s) {
      const int ck = 2*s + hl;
      bf16x8 af = as_bf(*(const short8*)(shE + lo*128 + (((ck ^ (lo & 15)) & 15) << 3)));
      acc2 = __builtin_amdgcn_mfma_f32_32x32x16_bf16(af, wb2[s], acc2, 0, 0, 0);
    }
    // epilogue 2: silu, *cw2, accumulate S / SX / SY (upd = pos_i*S - S*pos_j)
#pragma unroll
    for (int r = 0; r < 16; ++r) {
      int row = (r&3) + 8*(r>>2) + hl4;
      float p = silu_f(acc2[r] + cb1v) * c2v + cb2c;
      S += p;
      SX += p * __shfl(pjx, row, 32);
      SY += p * __shfl(pjy, row, 32);
    }
  }

  // ---- msg writeout (combine the two k-halves)
  msum += __shfl_xor(msum, 32);
  if (l < 32) ws[WS_MSG + node*128 + 32*w + lo] = msum;

  // ---- coordinate update reduction
#pragma unroll
  for (int off = 32; off > 0; off >>= 1) {
    S  += __shfl_xor(S, off);
    SX += __shfl_xor(SX, off);
    SY += __shfl_xor(SY, off);
  }
  if (l == 0) { shred[w] = S; shred[4 + w] = SX; shred[8 + w] = SY; }
  __syncthreads();
  if (t == 0) {
    float St  = shred[0] + shred[1] + shred[2]  + shred[3];
    float SXt = shred[4] + shred[5] + shred[6]  + shred[7];
    float SYt = shred[8] + shred[9] + shred[10] + shred[11];
    float updx = pix*St - SXt, updy = piy*St - SYt;
    out[OUT_POS + node*2+0] = pix + updx;
    out[OUT_POS + node*2+1] = piy + updy;
    out[OUT_VEL + node*2+0] = vel[node*2+0] + 0.1f*updx;
    out[OUT_VEL + node*2+1] = vel[node*2+1] + 0.1f*updy;
  }
}

// ---------------------------------------------------------------- K4
__global__ __launch_bounds__(128)
void k4_node(const float* __restrict__ h, const float* __restrict__ ws,
             const float* __restrict__ nw1, const float* __restrict__ nb1,
             const float* __restrict__ nw2, const float* __restrict__ nb2,
             const float* __restrict__ lng, const float* __restrict__ lnb,
             float* __restrict__ out) {
  int node = blockIdx.x;
  int t = threadIdx.x;
  __shared__ float sh_in[256];
  __shared__ float sh_hid[HID];
  __shared__ float rbuf[4];

  sh_in[t]       = h[node*HID + t];
  sh_in[HID + t] = ws[WS_MSG + (size_t)node*HID + t];
  __syncthreads();

  float s = nb1[t];
#pragma unroll 4
  for (int k = 0; k < 256; ++k) s += sh_in[k] * nw1[k*HID + t];
  sh_hid[t] = silu_f(s);
  __syncthreads();

  float hn = nb2[t];
#pragma unroll 4
  for (int k = 0; k < HID; ++k) hn += sh_hid[k] * nw2[k*HID + t];
  float x = sh_in[t] + hn;

  float v1 = x, v2 = x*x;
#pragma unroll
  for (int off = 32; off > 0; off >>= 1) {
    v1 += __shfl_down(v1, off);
    v2 += __shfl_down(v2, off);
  }
  if ((t & 63) == 0) { rbuf[t>>6] = v1; rbuf[2 + (t>>6)] = v2; }
  __syncthreads();
  float mu  = (rbuf[0] + rbuf[1]) * (1.f/HID);
  float var = (rbuf[2] + rbuf[3]) * (1.f/HID) - mu*mu;
  float inv = 1.f / sqrtf(var + 1e-5f);
  out[node*HID + t] = (x - mu) * inv * lng[t] + lnb[t];
}

// ---------------------------------------------------------------- launch
extern "C" void kernel_launch(void* const* d_in, const int* in_sizes, int n_in,
                              void* d_out, int out_size, void* d_ws, size_t ws_size,
                              hipStream_t stream) {
  (void)in_sizes; (void)n_in; (void)out_size; (void)ws_size;
  const float* h   = (const float*)d_in[0];
  const float* pos = (const float*)d_in[1];
  const float* vel = (const float*)d_in[2];
  const float* ew1 = (const float*)d_in[3];
  const float* eb1 = (const float*)d_in[4];
  const float* ew2 = (const float*)d_in[5];
  const float* eb2 = (const float*)d_in[6];
  const float* cw1 = (const float*)d_in[7];
  const float* cb1 = (const float*)d_in[8];
  const float* cw2 = (const float*)d_in[9];
  const float* cb2 = (const float*)d_in[10];
  const float* nw1 = (const float*)d_in[11];
  const float* nb1 = (const float*)d_in[12];
  const float* nw2 = (const float*)d_in[13];
  const float* nb2 = (const float*)d_in[14];
  const float* lng = (const float*)d_in[15];
  const float* lnb = (const float*)d_in[16];
  float* out = (float*)d_out;
  float* ws  = (float*)d_ws;
  unsigned short* wsU = (unsigned short*)d_ws;

  hipLaunchKernelGGL(k0_prep, dim3(208), dim3(256), 0, stream, ew1, ew2, cw1, wsU);
  hipLaunchKernelGGL(k1_precompute, dim3(NNODE), dim3(256), 0, stream, h, ew1, eb1, ws, wsU);
  hipLaunchKernelGGL(k3_edge, dim3(NNODE), dim3(256), 0, stream,
                     pos, vel, eb2, cb1, cw2, cb2, ws, out);
  hipLaunchKernelGGL(k4_node, dim3(NNODE), dim3(128), 0, stream,
                     h, ws, nw1, nb1, nw2, nb2, lng, lnb, out);
}